// Round 1
// baseline (526.029 us; speedup 1.0000x reference)
//
#include <hip/hip_runtime.h>
#include <hip/hip_bf16.h>

#define D  128
#define KN 32

typedef __attribute__((ext_vector_type(8))) short bf16x8;
typedef __attribute__((ext_vector_type(4))) float f32x4;

static __device__ __forceinline__ unsigned short f2bf(float f) {
    union { float f; unsigned int u; } v; v.f = f;
    unsigned int u = v.u;
    u += 0x7fff + ((u >> 16) & 1);   // round-to-nearest-even
    return (unsigned short)(u >> 16);
}
static __device__ __forceinline__ float bf2f(unsigned short h) {
    union { float f; unsigned int u; } v; v.u = ((unsigned int)h) << 16;
    return v.f;
}

// One-shot: transpose+convert W1 halves and W2 into bf16 [col][k] layouts.
__global__ __launch_bounds__(256) void wt_kernel(
    const float* __restrict__ W1, const float* __restrict__ W2,
    unsigned short* __restrict__ W1Tt, unsigned short* __restrict__ W1Tb,
    unsigned short* __restrict__ W2T)
{
    int idx = blockIdx.x * 256 + threadIdx.x;
    if (idx < D * D) {
        int col = idx >> 7, e = idx & 127;
        W1Tt[col * D + e] = f2bf(W1[e * D + col]);
        W1Tb[col * D + e] = f2bf(W1[(D + e) * D + col]);
        W2T [col * D + e] = f2bf(W2[e * D + col]);
    }
}

// Fused P1/Q producer. PE layout per video v (512B row, stride 256 ushorts):
//   PE[v][  0..127] = P1 row  (emb[v] @ W1top, bf16)
//   PE[v][128..255] = EB row  (bf16 copy of emb[v])
// Blocks [0,nvBlocks): PE rows. Blocks [nvBlocks,..): Q = emb[vnodes]@W1bot + b1.
// Epilogue restages C through sA so global stores are 16B-coalesced (was 64
// scalar ushort stores/thread).
__global__ __launch_bounds__(256) void p1q_kernel(
    const float* __restrict__ emb, const int* __restrict__ vnodes,
    int NV, int NN, int nvBlocks,
    const unsigned short* __restrict__ W1Tt, const unsigned short* __restrict__ W1Tb,
    const float* __restrict__ b1,
    unsigned short* __restrict__ PE, unsigned short* __restrict__ Q)
{
    __shared__ unsigned short sA[128][136];

    const int tid  = threadIdx.x;
    const int lane = tid & 63;
    const int w    = tid >> 6;
    const int m    = lane & 15, q = lane >> 4;

    const bool nv = (int)blockIdx.x < nvBlocks;
    const int  bi = nv ? blockIdx.x : blockIdx.x - nvBlocks;
    const int  M  = nv ? NV : NN;
    const unsigned short* WT = nv ? W1Tt : W1Tb;
    const int r0 = bi * 128;

    // stage 128 rows fp32->bf16 (coalesced float4 stream / gather)
#pragma unroll
    for (int i = 0; i < 16; ++i) {
        int e = tid + 256 * i;
        int row = e >> 5, c4 = (e & 31) << 2;
        int r = r0 + row; if (r > M - 1) r = M - 1;
        int vr = nv ? r : vnodes[r];
        const float4 f = *(const float4*)(emb + (long)vr * D + c4);
        ushort4 h;
        h.x = f2bf(f.x); h.y = f2bf(f.y); h.z = f2bf(f.z); h.w = f2bf(f.w);
        *(ushort4*)(&sA[row][c4]) = h;
    }
    __syncthreads();

    // fused bf16-emb emission into PE second half (identity pass only)
    if (nv) {
        int row = tid >> 1, half = tid & 1;
        if (r0 + row < M) {
#pragma unroll
            for (int j = 0; j < 8; ++j)
                *(bf16x8*)(PE + (long)(r0 + row) * 256 + 128 + half * 64 + j * 8) =
                    *(const bf16x8*)(&sA[row][half * 64 + j * 8]);
        }
    }

    bf16x8 Bf[2][4];
#pragma unroll
    for (int nt = 0; nt < 2; ++nt)
#pragma unroll
        for (int kk = 0; kk < 4; ++kk)
            Bf[nt][kk] = *(const bf16x8*)(WT + (32 * w + 16 * nt + m) * D + kk * 32 + q * 8);
    float bv[2];
#pragma unroll
    for (int nt = 0; nt < 2; ++nt) bv[nt] = nv ? 0.f : b1[32 * w + 16 * nt + m];

    f32x4 acc[8][2];
#pragma unroll
    for (int mt = 0; mt < 8; ++mt)
#pragma unroll
        for (int nt = 0; nt < 2; ++nt) acc[mt][nt] = (f32x4){0.f, 0.f, 0.f, 0.f};

#pragma unroll
    for (int kk = 0; kk < 4; ++kk) {
#pragma unroll
        for (int mt = 0; mt < 8; ++mt) {
            bf16x8 a = *(const bf16x8*)(&sA[16 * mt + m][kk * 32 + q * 8]);
            acc[mt][0] = __builtin_amdgcn_mfma_f32_16x16x32_bf16(a, Bf[0][kk], acc[mt][0], 0, 0, 0);
            acc[mt][1] = __builtin_amdgcn_mfma_f32_16x16x32_bf16(a, Bf[1][kk], acc[mt][1], 0, 0, 0);
        }
    }

    // ---- coalesced epilogue: restage C into sA, then stream 16B stores ----
    __syncthreads();   // all A-reads of sA complete
    // C/D layout: col=lane&15, row=(lane>>4)*4+reg
#pragma unroll
    for (int mt = 0; mt < 8; ++mt)
#pragma unroll
        for (int nt = 0; nt < 2; ++nt) {
            int col = 32 * w + 16 * nt + m;
#pragma unroll
            for (int r = 0; r < 4; ++r)
                sA[16 * mt + 4 * q + r][col] = f2bf(acc[mt][nt][r] + bv[nt]);
        }
    __syncthreads();
    {
        int row = tid >> 1, half = tid & 1;
        int gr = r0 + row;
        if (gr < M) {
            if (nv) {
#pragma unroll
                for (int j = 0; j < 8; ++j)
                    *(bf16x8*)(PE + (long)gr * 256 + half * 64 + j * 8) =
                        *(const bf16x8*)(&sA[row][half * 64 + j * 8]);
            } else {
#pragma unroll
                for (int j = 0; j < 8; ++j)
                    *(bf16x8*)(Q + (long)gr * D + half * 64 + j * 8) =
                        *(const bf16x8*)(&sA[row][half * 64 + j * 8]);
            }
        }
    }
}

// Per-wave aggregator: one node per wave, zero barriers in the node loop.
// A-fragments (X = relu(P1+Q)) are gathered straight into registers using the
// 16x16x32 A layout (lane = row(l&15), k = kk*32 + (l>>4)*8). W2 fragments are
// staged once per block in fragment-linear LDS (16B/lane contiguous ->
// conflict-free ds_read_b128). Scores + softmax are pure in-wave shuffles.
__global__ __launch_bounds__(256, 4) void agg_kernel(
    const unsigned short* __restrict__ PE, const int* __restrict__ nidx,
    const unsigned short* __restrict__ W2T, const float* __restrict__ b2,
    const float* __restrict__ W3, const float* __restrict__ b3,
    const unsigned short* __restrict__ Q,
    float* __restrict__ out, int NN)
{
    __shared__ bf16x8 sB[2048];          // [kk*8+nt][lane], 32 KB
    __shared__ float  sB2[D], sW3[D];

    const int tid  = threadIdx.x;
    const int lane = tid & 63;
    const int w    = tid >> 6;
    const int m    = lane & 15, q = lane >> 4;

    // stage W2T into fragment-linear order
#pragma unroll
    for (int i = 0; i < 8; ++i) {
        int f  = tid + 256 * i;
        int fi = f >> 6, l = f & 63;
        int kk = fi >> 3, nt = fi & 7;
        sB[f] = *(const bf16x8*)(W2T + ((nt * 16 + (l & 15)) << 7) + kk * 32 + (l >> 4) * 8);
    }
    if (tid < D) { sB2[tid] = b2[tid]; sW3[tid] = W3[tid]; }
    __syncthreads();

    const float b3s = b3[0];
    const int nwaves = gridDim.x << 2;

    for (int node = (blockIdx.x << 2) + w; node < NN; node += nwaves) {
        int iv = (lane < KN) ? nidx[node * KN + lane] : 0;
        const int ik0 = __shfl(iv, m);          // row 16*0 + m
        const int ik1 = __shfl(iv, 16 + m);     // row 16*1 + m

        // gather P1 + Q fragments (12 independent 16B loads)
        bf16x8 p0[4], p1[4], qv[4];
        const unsigned short* prow0 = PE + (long)ik0 * 256 + q * 8;
        const unsigned short* prow1 = PE + (long)ik1 * 256 + q * 8;
        const unsigned short* qrow  = Q  + (long)node * D + q * 8;
#pragma unroll
        for (int kk = 0; kk < 4; ++kk) {
            p0[kk] = *(const bf16x8*)(prow0 + kk * 32);
            p1[kk] = *(const bf16x8*)(prow1 + kk * 32);
            qv[kk] = *(const bf16x8*)(qrow  + kk * 32);
        }

        // X = relu(P1 + Q) directly in A-fragment registers
        bf16x8 A0[4], A1[4];
#pragma unroll
        for (int kk = 0; kk < 4; ++kk) {
#pragma unroll
            for (int h = 0; h < 8; ++h) {
                float qf = bf2f((unsigned short)qv[kk][h]);
                float v0 = bf2f((unsigned short)p0[kk][h]) + qf;
                float v1 = bf2f((unsigned short)p1[kk][h]) + qf;
                A0[kk][h] = (short)f2bf(v0 > 0.f ? v0 : 0.f);
                A1[kk][h] = (short)f2bf(v1 > 0.f ? v1 : 0.f);
            }
        }

        // layer-2 GEMM: [32 x 128] = X @ W2, all 8 N-tiles in this wave
        f32x4 acc[2][8];
#pragma unroll
        for (int mt = 0; mt < 2; ++mt)
#pragma unroll
            for (int nt = 0; nt < 8; ++nt) acc[mt][nt] = (f32x4){0.f, 0.f, 0.f, 0.f};

#pragma unroll
        for (int kk = 0; kk < 4; ++kk) {
#pragma unroll
            for (int nt = 0; nt < 8; ++nt) {
                bf16x8 b = sB[((kk << 3) + nt) * 64 + lane];
                acc[0][nt] = __builtin_amdgcn_mfma_f32_16x16x32_bf16(A0[kk], b, acc[0][nt], 0, 0, 0);
                acc[1][nt] = __builtin_amdgcn_mfma_f32_16x16x32_bf16(A1[kk], b, acc[1][nt], 0, 0, 0);
            }
        }

        // scores: relu(acc + b2) . W3, reduced across the 16 col-lanes
        float s[2][4];
#pragma unroll
        for (int mt = 0; mt < 2; ++mt) {
#pragma unroll
            for (int r = 0; r < 4; ++r) s[mt][r] = 0.f;
#pragma unroll
            for (int nt = 0; nt < 8; ++nt) {
                float bc = sB2[nt * 16 + m], wc = sW3[nt * 16 + m];
#pragma unroll
                for (int r = 0; r < 4; ++r) {
                    float h = acc[mt][nt][r] + bc;
                    s[mt][r] += (h > 0.f ? h : 0.f) * wc;
                }
            }
#pragma unroll
            for (int off = 8; off >= 1; off >>= 1)
#pragma unroll
                for (int r = 0; r < 4; ++r) s[mt][r] += __shfl_xor(s[mt][r], off, 16);
#pragma unroll
            for (int r = 0; r < 4; ++r) s[mt][r] += b3s;
        }
        // lane holds scores for k = 16*mt + 4*q + r; softmax over 32
        float mx = s[0][0];
#pragma unroll
        for (int mt = 0; mt < 2; ++mt)
#pragma unroll
            for (int r = 0; r < 4; ++r) mx = fmaxf(mx, s[mt][r]);
        mx = fmaxf(mx, __shfl_xor(mx, 16));
        mx = fmaxf(mx, __shfl_xor(mx, 32));
        float e[2][4], sum = 0.f;
#pragma unroll
        for (int mt = 0; mt < 2; ++mt)
#pragma unroll
            for (int r = 0; r < 4; ++r) { e[mt][r] = __expf(s[mt][r] - mx); sum += e[mt][r]; }
        sum += __shfl_xor(sum, 16);
        sum += __shfl_xor(sum, 32);
        const float inv = 1.f / sum;

        // aggregation: gather EB rows (att weight for row k_j is lane-local)
        bf16x8 gv[8];
#pragma unroll
        for (int j = 0; j < 8; ++j) {
            int kj  = 4 * q + (j & 3) + 16 * (j >> 2);
            int ikj = __shfl(iv, kj);
            gv[j] = *(const bf16x8*)(PE + (long)ikj * 256 + 128 + m * 8);
        }
        float r8[8] = {0.f, 0.f, 0.f, 0.f, 0.f, 0.f, 0.f, 0.f};
#pragma unroll
        for (int j = 0; j < 8; ++j) {
            float a = e[j >> 2][j & 3] * inv;
#pragma unroll
            for (int h = 0; h < 8; ++h) r8[h] += a * bf2f((unsigned short)gv[j][h]);
        }
#pragma unroll
        for (int h = 0; h < 8; ++h) {
            r8[h] += __shfl_xor(r8[h], 16);
            r8[h] += __shfl_xor(r8[h], 32);
        }
        if (lane < 16) {
            float4 o0 = {r8[0], r8[1], r8[2], r8[3]};
            float4 o1 = {r8[4], r8[5], r8[6], r8[7]};
            *(float4*)(out + (long)node * D + m * 8)     = o0;
            *(float4*)(out + (long)node * D + m * 8 + 4) = o1;
        }
    }
}

// Correct-but-slow fp32 VALU fallback (only if ws is too small).
__global__ __launch_bounds__(128) void naive_kernel(
    const float* __restrict__ emb, const int* __restrict__ vnodes,
    const int* __restrict__ nidx,
    const float* __restrict__ W1, const float* __restrict__ b1,
    const float* __restrict__ W2, const float* __restrict__ b2,
    const float* __restrict__ W3, const float* __restrict__ b3,
    float* __restrict__ out)
{
    __shared__ float sE[KN + 1][D];
    __shared__ float sH[KN][D];
    __shared__ float sH2[KN][D];
    __shared__ float sS[KN];
    __shared__ float sA2[KN];
    const int node = blockIdx.x, tid = threadIdx.x;

    for (int r = 0; r < KN + 1; ++r) {
        int vr = (r < KN) ? nidx[node * KN + r] : vnodes[node];
        sE[r][tid] = emb[(long)vr * D + tid];
    }
    __syncthreads();
    for (int k = 0; k < KN; ++k) {
        float s = b1[tid];
        for (int e = 0; e < D; ++e) s += sE[k][e]  * W1[e * D + tid];
        for (int e = 0; e < D; ++e) s += sE[KN][e] * W1[(D + e) * D + tid];
        sH[k][tid] = s > 0.f ? s : 0.f;
    }
    __syncthreads();
    for (int k = 0; k < KN; ++k) {
        float s = b2[tid];
        for (int e = 0; e < D; ++e) s += sH[k][e] * W2[e * D + tid];
        sH2[k][tid] = s > 0.f ? s : 0.f;
    }
    __syncthreads();
    if (tid < KN) {
        float s = b3[0];
        for (int e = 0; e < D; ++e) s += sH2[tid][e] * W3[e];
        sS[tid] = s;
    }
    __syncthreads();
    if (tid == 0) {
        float mx = sS[0];
        for (int k = 1; k < KN; ++k) mx = fmaxf(mx, sS[k]);
        float sum = 0.f;
        for (int k = 0; k < KN; ++k) { sA2[k] = __expf(sS[k] - mx); sum += sA2[k]; }
        for (int k = 0; k < KN; ++k) sA2[k] /= sum;
    }
    __syncthreads();
    float a = 0.f;
    for (int k = 0; k < KN; ++k) a += sA2[k] * sE[k][tid];
    out[(long)node * D + tid] = a;
}

extern "C" void kernel_launch(void* const* d_in, const int* in_sizes, int n_in,
                              void* d_out, int out_size, void* d_ws, size_t ws_size,
                              hipStream_t stream) {
    const float* emb    = (const float*)d_in[0];
    const int*   vnodes = (const int*)d_in[1];
    const int*   nidx   = (const int*)d_in[2];
    const float* W1     = (const float*)d_in[3];
    const float* b1     = (const float*)d_in[4];
    const float* W2     = (const float*)d_in[5];
    const float* b2     = (const float*)d_in[6];
    const float* W3     = (const float*)d_in[7];
    const float* b3     = (const float*)d_in[8];
    float* out = (float*)d_out;

    const int NV = in_sizes[0] / D;   // 200000
    const int NN = in_sizes[1];       // 20000

    const size_t pe_elems = (size_t)NV * 256;        // P1+EB interleaved, 512B/row
    const size_t q_elems  = (size_t)NN * D;
    const size_t wt_elems = (size_t)D * D;
    const size_t need = (pe_elems + q_elems + 3 * wt_elems) * sizeof(unsigned short);

    if (ws_size >= need) {
        unsigned short* PE   = (unsigned short*)d_ws;
        unsigned short* Q    = PE + pe_elems;
        unsigned short* W1Tt = Q + q_elems;
        unsigned short* W1Tb = W1Tt + wt_elems;
        unsigned short* W2T  = W1Tb + wt_elems;

        const int nvBlocks = (NV + 127) / 128;
        const int qBlocks  = (NN + 127) / 128;

        wt_kernel<<<(D * D + 255) / 256, 256, 0, stream>>>(W1, W2, W1Tt, W1Tb, W2T);
        p1q_kernel<<<nvBlocks + qBlocks, 256, 0, stream>>>(
            emb, vnodes, NV, NN, nvBlocks, W1Tt, W1Tb, b1, PE, Q);
        agg_kernel<<<1024, 256, 0, stream>>>(
            PE, nidx, W2T, b2, W3, b3, Q, out, NN);
    } else {
        naive_kernel<<<NN, D, 0, stream>>>(emb, vnodes, nidx, W1, b1, W2, b2, W3, b3, out);
    }
}

// Round 2
// 355.729 us; speedup vs baseline: 1.4787x; 1.4787x over previous
//
#include <hip/hip_runtime.h>
#include <hip/hip_bf16.h>

#define D  128
#define KN 32

typedef __attribute__((ext_vector_type(8))) short bf16x8;
typedef __attribute__((ext_vector_type(4))) float f32x4;

static __device__ __forceinline__ unsigned short f2bf(float f) {
    union { float f; unsigned int u; } v; v.f = f;
    unsigned int u = v.u;
    u += 0x7fff + ((u >> 16) & 1);   // round-to-nearest-even
    return (unsigned short)(u >> 16);
}
static __device__ __forceinline__ float bf2f(unsigned short h) {
    union { float f; unsigned int u; } v; v.u = ((unsigned int)h) << 16;
    return v.f;
}

// One-shot: transpose+convert W1 halves and W2 into bf16 [col][k] layouts.
__global__ __launch_bounds__(256) void wt_kernel(
    const float* __restrict__ W1, const float* __restrict__ W2,
    unsigned short* __restrict__ W1Tt, unsigned short* __restrict__ W1Tb,
    unsigned short* __restrict__ W2T)
{
    int idx = blockIdx.x * 256 + threadIdx.x;
    if (idx < D * D) {
        int col = idx >> 7, e = idx & 127;
        W1Tt[col * D + e] = f2bf(W1[e * D + col]);
        W1Tb[col * D + e] = f2bf(W1[(D + e) * D + col]);
        W2T [col * D + e] = f2bf(W2[e * D + col]);
    }
}

// Fused P1/Q producer. PE layout per video v (512B row, stride 256 ushorts):
//   PE[v][  0..127] = P1 row  (emb[v] @ W1top, bf16)
//   PE[v][128..255] = EB row  (bf16 copy of emb[v])
// Blocks [0,nvBlocks): PE rows. Blocks [nvBlocks,..): Q = emb[vnodes]@W1bot + b1.
__global__ __launch_bounds__(256) void p1q_kernel(
    const float* __restrict__ emb, const int* __restrict__ vnodes,
    int NV, int NN, int nvBlocks,
    const unsigned short* __restrict__ W1Tt, const unsigned short* __restrict__ W1Tb,
    const float* __restrict__ b1,
    unsigned short* __restrict__ PE, unsigned short* __restrict__ Q)
{
    __shared__ unsigned short sA[128][136];

    const int tid  = threadIdx.x;
    const int lane = tid & 63;
    const int w    = tid >> 6;
    const int m    = lane & 15, q = lane >> 4;

    const bool nv = (int)blockIdx.x < nvBlocks;
    const int  bi = nv ? blockIdx.x : blockIdx.x - nvBlocks;
    const int  M  = nv ? NV : NN;
    const unsigned short* WT = nv ? W1Tt : W1Tb;
    const int r0 = bi * 128;

    // stage 128 rows fp32->bf16 (coalesced float4 stream / gather)
#pragma unroll
    for (int i = 0; i < 16; ++i) {
        int e = tid + 256 * i;
        int row = e >> 5, c4 = (e & 31) << 2;
        int r = r0 + row; if (r > M - 1) r = M - 1;
        int vr = nv ? r : vnodes[r];
        const float4 f = *(const float4*)(emb + (long)vr * D + c4);
        ushort4 h;
        h.x = f2bf(f.x); h.y = f2bf(f.y); h.z = f2bf(f.z); h.w = f2bf(f.w);
        *(ushort4*)(&sA[row][c4]) = h;
    }
    __syncthreads();

    // fused bf16-emb emission into PE second half (identity pass only)
    if (nv) {
        int row = tid >> 1, half = tid & 1;
        if (r0 + row < M) {
#pragma unroll
            for (int j = 0; j < 8; ++j)
                *(bf16x8*)(PE + (long)(r0 + row) * 256 + 128 + half * 64 + j * 8) =
                    *(const bf16x8*)(&sA[row][half * 64 + j * 8]);
        }
    }

    bf16x8 Bf[2][4];
#pragma unroll
    for (int nt = 0; nt < 2; ++nt)
#pragma unroll
        for (int kk = 0; kk < 4; ++kk)
            Bf[nt][kk] = *(const bf16x8*)(WT + (32 * w + 16 * nt + m) * D + kk * 32 + q * 8);
    float bv[2];
#pragma unroll
    for (int nt = 0; nt < 2; ++nt) bv[nt] = nv ? 0.f : b1[32 * w + 16 * nt + m];

    f32x4 acc[8][2];
#pragma unroll
    for (int mt = 0; mt < 8; ++mt)
#pragma unroll
        for (int nt = 0; nt < 2; ++nt) acc[mt][nt] = (f32x4){0.f, 0.f, 0.f, 0.f};

#pragma unroll
    for (int kk = 0; kk < 4; ++kk) {
#pragma unroll
        for (int mt = 0; mt < 8; ++mt) {
            bf16x8 a = *(const bf16x8*)(&sA[16 * mt + m][kk * 32 + q * 8]);
            acc[mt][0] = __builtin_amdgcn_mfma_f32_16x16x32_bf16(a, Bf[0][kk], acc[mt][0], 0, 0, 0);
            acc[mt][1] = __builtin_amdgcn_mfma_f32_16x16x32_bf16(a, Bf[1][kk], acc[mt][1], 0, 0, 0);
        }
    }

    // ---- coalesced epilogue: restage C into sA, then stream 16B stores ----
    __syncthreads();   // all A-reads of sA complete
    // C/D layout: col=lane&15, row=(lane>>4)*4+reg
#pragma unroll
    for (int mt = 0; mt < 8; ++mt)
#pragma unroll
        for (int nt = 0; nt < 2; ++nt) {
            int col = 32 * w + 16 * nt + m;
#pragma unroll
            for (int r = 0; r < 4; ++r)
                sA[16 * mt + 4 * q + r][col] = f2bf(acc[mt][nt][r] + bv[nt]);
        }
    __syncthreads();
    {
        int row = tid >> 1, half = tid & 1;
        int gr = r0 + row;
        if (gr < M) {
            if (nv) {
#pragma unroll
                for (int j = 0; j < 8; ++j)
                    *(bf16x8*)(PE + (long)gr * 256 + half * 64 + j * 8) =
                        *(const bf16x8*)(&sA[row][half * 64 + j * 8]);
            } else {
#pragma unroll
                for (int j = 0; j < 8; ++j)
                    *(bf16x8*)(Q + (long)gr * D + half * 64 + j * 8) =
                        *(const bf16x8*)(&sA[row][half * 64 + j * 8]);
            }
        }
    }
}

// Per-wave aggregator: one node per wave, zero barriers in the node loop,
// software-pipelined across nodes.
//   - gv (EB rows) issued at iter top -> in flight under convert+MFMA+scores
//   - next node's nidx row issued before MFMA
//   - next node's 12 P1/Q fragment loads issued after softmax (dest regs are
//     free once the A-conversion consumed them)
// __launch_bounds__(256,2): 256-reg budget (acc 64 AGPR + ~150 VGPR), no
// spills (round-1's (256,4)=128-reg cap caused 360 MB/dispatch scratch
// traffic). 2 blocks/CU = 8 independent waves/CU.
__global__ __launch_bounds__(256, 2) void agg_kernel(
    const unsigned short* __restrict__ PE, const int* __restrict__ nidx,
    const unsigned short* __restrict__ W2T, const float* __restrict__ b2,
    const float* __restrict__ W3, const float* __restrict__ b3,
    const unsigned short* __restrict__ Q,
    float* __restrict__ out, int NN)
{
    __shared__ bf16x8 sB[2048];          // [kk*8+nt][lane], 32 KB, frag-linear
    __shared__ float  sB2[D], sW3[D];

    const int tid  = threadIdx.x;
    const int lane = tid & 63;
    const int w    = tid >> 6;
    const int m    = lane & 15, q = lane >> 4;

    // stage W2T into fragment-linear order (16B/lane contiguous -> 0 conflicts)
#pragma unroll
    for (int i = 0; i < 8; ++i) {
        int f  = tid + 256 * i;
        int fi = f >> 6, l = f & 63;
        int kk = fi >> 3, nt = fi & 7;
        sB[f] = *(const bf16x8*)(W2T + ((nt * 16 + (l & 15)) << 7) + kk * 32 + (l >> 4) * 8);
    }
    if (tid < D) { sB2[tid] = b2[tid]; sW3[tid] = W3[tid]; }
    __syncthreads();

    const float b3s = b3[0];
    const int stride = gridDim.x << 2;
    int node = (blockIdx.x << 2) + w;

    // ---- pipeline prologue: first node's index row + P1/Q fragments ----
    int iv = 0;
    bf16x8 pf0[4], pf1[4], qf[4];
    if (node < NN) {
        iv = (lane < KN) ? nidx[node * KN + lane] : 0;
        const int ik0 = __shfl(iv, m);
        const int ik1 = __shfl(iv, 16 + m);
        const unsigned short* pr0 = PE + (long)ik0 * 256 + q * 8;
        const unsigned short* pr1 = PE + (long)ik1 * 256 + q * 8;
        const unsigned short* qr  = Q  + (long)node * D + q * 8;
#pragma unroll
        for (int kk = 0; kk < 4; ++kk) {
            pf0[kk] = *(const bf16x8*)(pr0 + kk * 32);
            pf1[kk] = *(const bf16x8*)(pr1 + kk * 32);
            qf[kk]  = *(const bf16x8*)(qr  + kk * 32);
        }
    }

    for (; node < NN; node += stride) {
        // ---- issue EB gather for current node (consumed at iter end) ----
        bf16x8 gv[8];
#pragma unroll
        for (int j = 0; j < 8; ++j) {
            int kj  = 4 * q + (j & 3) + 16 * (j >> 2);
            int ikj = __shfl(iv, kj);
            gv[j] = *(const bf16x8*)(PE + (long)ikj * 256 + 128 + m * 8);
        }

        // ---- X = relu(P1 + Q) directly in A-fragment registers ----
        bf16x8 A0[4], A1[4];
#pragma unroll
        for (int kk = 0; kk < 4; ++kk) {
#pragma unroll
            for (int h = 0; h < 8; ++h) {
                float qv = bf2f((unsigned short)qf[kk][h]);
                float v0 = bf2f((unsigned short)pf0[kk][h]) + qv;
                float v1 = bf2f((unsigned short)pf1[kk][h]) + qv;
                A0[kk][h] = (short)f2bf(v0 > 0.f ? v0 : 0.f);
                A1[kk][h] = (short)f2bf(v1 > 0.f ? v1 : 0.f);
            }
        }

        // ---- next node's index row (needed after softmax) ----
        const int noden = node + stride;
        const bool more = noden < NN;
        int ivn = 0;
        if (more) ivn = (lane < KN) ? nidx[noden * KN + lane] : 0;

        // ---- layer-2 GEMM: [32 x 128] = X @ W2, 8 N-tiles in this wave ----
        f32x4 acc[2][8];
#pragma unroll
        for (int mt = 0; mt < 2; ++mt)
#pragma unroll
            for (int nt = 0; nt < 8; ++nt) acc[mt][nt] = (f32x4){0.f, 0.f, 0.f, 0.f};

#pragma unroll
        for (int kk = 0; kk < 4; ++kk) {
#pragma unroll
            for (int nt = 0; nt < 8; ++nt) {
                bf16x8 b = sB[((kk << 3) + nt) * 64 + lane];
                acc[0][nt] = __builtin_amdgcn_mfma_f32_16x16x32_bf16(A0[kk], b, acc[0][nt], 0, 0, 0);
                acc[1][nt] = __builtin_amdgcn_mfma_f32_16x16x32_bf16(A1[kk], b, acc[1][nt], 0, 0, 0);
            }
        }

        // ---- scores: relu(acc + b2) . W3, reduced across 16 col-lanes ----
        float s[2][4];
#pragma unroll
        for (int mt = 0; mt < 2; ++mt) {
#pragma unroll
            for (int r = 0; r < 4; ++r) s[mt][r] = 0.f;
#pragma unroll
            for (int nt = 0; nt < 8; ++nt) {
                float bc = sB2[nt * 16 + m], wc = sW3[nt * 16 + m];
#pragma unroll
                for (int r = 0; r < 4; ++r) {
                    float h = acc[mt][nt][r] + bc;
                    s[mt][r] += (h > 0.f ? h : 0.f) * wc;
                }
            }
#pragma unroll
            for (int off = 8; off >= 1; off >>= 1)
#pragma unroll
                for (int r = 0; r < 4; ++r) s[mt][r] += __shfl_xor(s[mt][r], off, 16);
#pragma unroll
            for (int r = 0; r < 4; ++r) s[mt][r] += b3s;
        }

        // ---- softmax over 32 (lane holds k = 16*mt + 4*q + r) ----
        float mx = s[0][0];
#pragma unroll
        for (int mt = 0; mt < 2; ++mt)
#pragma unroll
            for (int r = 0; r < 4; ++r) mx = fmaxf(mx, s[mt][r]);
        mx = fmaxf(mx, __shfl_xor(mx, 16));
        mx = fmaxf(mx, __shfl_xor(mx, 32));
        float e[2][4], sum = 0.f;
#pragma unroll
        for (int mt = 0; mt < 2; ++mt)
#pragma unroll
            for (int r = 0; r < 4; ++r) { e[mt][r] = __expf(s[mt][r] - mx); sum += e[mt][r]; }
        sum += __shfl_xor(sum, 16);
        sum += __shfl_xor(sum, 32);
        const float inv = 1.f / sum;

        // ---- prefetch next node's P1/Q fragments (regs freed by convert) ----
        if (more) {
            const int ik0n = __shfl(ivn, m);
            const int ik1n = __shfl(ivn, 16 + m);
            const unsigned short* pr0 = PE + (long)ik0n * 256 + q * 8;
            const unsigned short* pr1 = PE + (long)ik1n * 256 + q * 8;
            const unsigned short* qr  = Q  + (long)noden * D + q * 8;
#pragma unroll
            for (int kk = 0; kk < 4; ++kk) {
                pf0[kk] = *(const bf16x8*)(pr0 + kk * 32);
                pf1[kk] = *(const bf16x8*)(pr1 + kk * 32);
                qf[kk]  = *(const bf16x8*)(qr  + kk * 32);
            }
        }

        // ---- aggregation from prefetched gv ----
        float r8[8] = {0.f, 0.f, 0.f, 0.f, 0.f, 0.f, 0.f, 0.f};
#pragma unroll
        for (int j = 0; j < 8; ++j) {
            float a = e[j >> 2][j & 3] * inv;
#pragma unroll
            for (int h = 0; h < 8; ++h) r8[h] += a * bf2f((unsigned short)gv[j][h]);
        }
#pragma unroll
        for (int h = 0; h < 8; ++h) {
            r8[h] += __shfl_xor(r8[h], 16);
            r8[h] += __shfl_xor(r8[h], 32);
        }
        if (lane < 16) {
            float4 o0 = {r8[0], r8[1], r8[2], r8[3]};
            float4 o1 = {r8[4], r8[5], r8[6], r8[7]};
            *(float4*)(out + (long)node * D + m * 8)     = o0;
            *(float4*)(out + (long)node * D + m * 8 + 4) = o1;
        }

        iv = ivn;
    }
}

// Correct-but-slow fp32 VALU fallback (only if ws is too small).
__global__ __launch_bounds__(128) void naive_kernel(
    const float* __restrict__ emb, const int* __restrict__ vnodes,
    const int* __restrict__ nidx,
    const float* __restrict__ W1, const float* __restrict__ b1,
    const float* __restrict__ W2, const float* __restrict__ b2,
    const float* __restrict__ W3, const float* __restrict__ b3,
    float* __restrict__ out)
{
    __shared__ float sE[KN + 1][D];
    __shared__ float sH[KN][D];
    __shared__ float sH2[KN][D];
    __shared__ float sS[KN];
    __shared__ float sA2[KN];
    const int node = blockIdx.x, tid = threadIdx.x;

    for (int r = 0; r < KN + 1; ++r) {
        int vr = (r < KN) ? nidx[node * KN + r] : vnodes[node];
        sE[r][tid] = emb[(long)vr * D + tid];
    }
    __syncthreads();
    for (int k = 0; k < KN; ++k) {
        float s = b1[tid];
        for (int e = 0; e < D; ++e) s += sE[k][e]  * W1[e * D + tid];
        for (int e = 0; e < D; ++e) s += sE[KN][e] * W1[(D + e) * D + tid];
        sH[k][tid] = s > 0.f ? s : 0.f;
    }
    __syncthreads();
    for (int k = 0; k < KN; ++k) {
        float s = b2[tid];
        for (int e = 0; e < D; ++e) s += sH[k][e] * W2[e * D + tid];
        sH2[k][tid] = s > 0.f ? s : 0.f;
    }
    __syncthreads();
    if (tid < KN) {
        float s = b3[0];
        for (int e = 0; e < D; ++e) s += sH2[tid][e] * W3[e];
        sS[tid] = s;
    }
    __syncthreads();
    if (tid == 0) {
        float mx = sS[0];
        for (int k = 1; k < KN; ++k) mx = fmaxf(mx, sS[k]);
        float sum = 0.f;
        for (int k = 0; k < KN; ++k) { sA2[k] = __expf(sS[k] - mx); sum += sA2[k]; }
        for (int k = 0; k < KN; ++k) sA2[k] /= sum;
    }
    __syncthreads();
    float a = 0.f;
    for (int k = 0; k < KN; ++k) a += sA2[k] * sE[k][tid];
    out[(long)node * D + tid] = a;
}

extern "C" void kernel_launch(void* const* d_in, const int* in_sizes, int n_in,
                              void* d_out, int out_size, void* d_ws, size_t ws_size,
                              hipStream_t stream) {
    const float* emb    = (const float*)d_in[0];
    const int*   vnodes = (const int*)d_in[1];
    const int*   nidx   = (const int*)d_in[2];
    const float* W1     = (const float*)d_in[3];
    const float* b1     = (const float*)d_in[4];
    const float* W2     = (const float*)d_in[5];
    const float* b2     = (const float*)d_in[6];
    const float* W3     = (const float*)d_in[7];
    const float* b3     = (const float*)d_in[8];
    float* out = (float*)d_out;

    const int NV = in_sizes[0] / D;   // 200000
    const int NN = in_sizes[1];       // 20000

    const size_t pe_elems = (size_t)NV * 256;        // P1+EB interleaved, 512B/row
    const size_t q_elems  = (size_t)NN * D;
    const size_t wt_elems = (size_t)D * D;
    const size_t need = (pe_elems + q_elems + 3 * wt_elems) * sizeof(unsigned short);

    if (ws_size >= need) {
        unsigned short* PE   = (unsigned short*)d_ws;
        unsigned short* Q    = PE + pe_elems;
        unsigned short* W1Tt = Q + q_elems;
        unsigned short* W1Tb = W1Tt + wt_elems;
        unsigned short* W2T  = W1Tb + wt_elems;

        const int nvBlocks = (NV + 127) / 128;
        const int qBlocks  = (NN + 127) / 128;

        wt_kernel<<<(D * D + 255) / 256, 256, 0, stream>>>(W1, W2, W1Tt, W1Tb, W2T);
        p1q_kernel<<<nvBlocks + qBlocks, 256, 0, stream>>>(
            emb, vnodes, NV, NN, nvBlocks, W1Tt, W1Tb, b1, PE, Q);
        agg_kernel<<<512, 256, 0, stream>>>(
            PE, nidx, W2T, b2, W3, b3, Q, out, NN);
    } else {
        naive_kernel<<<NN, D, 0, stream>>>(emb, vnodes, nidx, W1, b1, W2, b2, W3, b3, out);
    }
}

// Round 3
// 316.915 us; speedup vs baseline: 1.6598x; 1.1225x over previous
//
#include <hip/hip_runtime.h>
#include <hip/hip_bf16.h>

#define D  128
#define KN 32

typedef __attribute__((ext_vector_type(8))) short bf16x8;
typedef __attribute__((ext_vector_type(4))) float f32x4;

static __device__ __forceinline__ unsigned short f2bf(float f) {
    union { float f; unsigned int u; } v; v.f = f;
    unsigned int u = v.u;
    u += 0x7fff + ((u >> 16) & 1);   // round-to-nearest-even
    return (unsigned short)(u >> 16);
}
static __device__ __forceinline__ float bf2f(unsigned short h) {
    union { float f; unsigned int u; } v; v.u = ((unsigned int)h) << 16;
    return v.f;
}

// One-shot: transpose+convert W1 halves and W2 into bf16 [col][k] layouts.
__global__ __launch_bounds__(256) void wt_kernel(
    const float* __restrict__ W1, const float* __restrict__ W2,
    unsigned short* __restrict__ W1Tt, unsigned short* __restrict__ W1Tb,
    unsigned short* __restrict__ W2T)
{
    int idx = blockIdx.x * 256 + threadIdx.x;
    if (idx < D * D) {
        int col = idx >> 7, e = idx & 127;
        W1Tt[col * D + e] = f2bf(W1[e * D + col]);
        W1Tb[col * D + e] = f2bf(W1[(D + e) * D + col]);
        W2T [col * D + e] = f2bf(W2[e * D + col]);
    }
}

// Fused P1/Q producer (separate P1 / EB / Q arrays, round-0 layout).
// Blocks [0,nvBlocks): P1 = emb@W1top (+ bf16 emb copy EB).
// Blocks [nvBlocks,..): Q = emb[vnodes]@W1bot + b1.
// All three output streams are stored with a linear byte mapping through LDS:
// each store instruction writes 4 KB fully contiguous (256 threads x 16B).
__global__ __launch_bounds__(256) void p1q_kernel(
    const float* __restrict__ emb, const int* __restrict__ vnodes,
    int NV, int NN, int nvBlocks,
    const unsigned short* __restrict__ W1Tt, const unsigned short* __restrict__ W1Tb,
    const float* __restrict__ b1,
    unsigned short* __restrict__ P1, unsigned short* __restrict__ Q,
    unsigned short* __restrict__ EB)
{
    __shared__ unsigned short sA[128][136];

    const int tid  = threadIdx.x;
    const int lane = tid & 63;
    const int w    = tid >> 6;
    const int m    = lane & 15, q = lane >> 4;

    const bool nv = (int)blockIdx.x < nvBlocks;
    const int  bi = nv ? blockIdx.x : blockIdx.x - nvBlocks;
    const int  M  = nv ? NV : NN;
    const unsigned short* WT = nv ? W1Tt : W1Tb;
    const int r0 = bi * 128;

    int maxRows = M - r0; if (maxRows > 128) maxRows = 128;
    const int maxB = maxRows << 8;          // valid bytes in this block's region

    // stage 128 rows fp32->bf16 (coalesced float4 stream / gather)
#pragma unroll
    for (int i = 0; i < 16; ++i) {
        int e = tid + 256 * i;
        int row = e >> 5, c4 = (e & 31) << 2;
        int r = r0 + row; if (r > M - 1) r = M - 1;
        int vr = nv ? r : vnodes[r];
        const float4 f = *(const float4*)(emb + (long)vr * D + c4);
        ushort4 h;
        h.x = f2bf(f.x); h.y = f2bf(f.y); h.z = f2bf(f.z); h.w = f2bf(f.w);
        *(ushort4*)(&sA[row][c4]) = h;
    }
    __syncthreads();

    // EB emission (pre-restage sA): fully-contiguous 4KB per instruction
    if (nv) {
        char* ebBase = (char*)(EB + (long)r0 * D);
#pragma unroll
        for (int j = 0; j < 8; ++j) {
            int p = j * 4096 + tid * 16;
            if (p < maxB) {
                int row = p >> 8, off = (p & 255) >> 1;
                *(bf16x8*)(ebBase + p) = *(const bf16x8*)(&sA[row][off]);
            }
        }
    }

    bf16x8 Bf[2][4];
#pragma unroll
    for (int nt = 0; nt < 2; ++nt)
#pragma unroll
        for (int kk = 0; kk < 4; ++kk)
            Bf[nt][kk] = *(const bf16x8*)(WT + (32 * w + 16 * nt + m) * D + kk * 32 + q * 8);
    float bv[2];
#pragma unroll
    for (int nt = 0; nt < 2; ++nt) bv[nt] = nv ? 0.f : b1[32 * w + 16 * nt + m];

    f32x4 acc[8][2];
#pragma unroll
    for (int mt = 0; mt < 8; ++mt)
#pragma unroll
        for (int nt = 0; nt < 2; ++nt) acc[mt][nt] = (f32x4){0.f, 0.f, 0.f, 0.f};

#pragma unroll
    for (int kk = 0; kk < 4; ++kk) {
#pragma unroll
        for (int mt = 0; mt < 8; ++mt) {
            bf16x8 a = *(const bf16x8*)(&sA[16 * mt + m][kk * 32 + q * 8]);
            acc[mt][0] = __builtin_amdgcn_mfma_f32_16x16x32_bf16(a, Bf[0][kk], acc[mt][0], 0, 0, 0);
            acc[mt][1] = __builtin_amdgcn_mfma_f32_16x16x32_bf16(a, Bf[1][kk], acc[mt][1], 0, 0, 0);
        }
    }

    // ---- restage C into sA, then fully-contiguous 4KB stores ----
    __syncthreads();   // all A-reads + EB-reads of sA complete
    // C/D layout: col=lane&15, row=(lane>>4)*4+reg
#pragma unroll
    for (int mt = 0; mt < 8; ++mt)
#pragma unroll
        for (int nt = 0; nt < 2; ++nt) {
            int col = 32 * w + 16 * nt + m;
#pragma unroll
            for (int r = 0; r < 4; ++r)
                sA[16 * mt + 4 * q + r][col] = f2bf(acc[mt][nt][r] + bv[nt]);
        }
    __syncthreads();
    {
        char* dstBase = (char*)((nv ? P1 : Q) + (long)r0 * D);
#pragma unroll
        for (int j = 0; j < 8; ++j) {
            int p = j * 4096 + tid * 16;
            if (p < maxB) {
                int row = p >> 8, off = (p & 255) >> 1;
                *(bf16x8*)(dstBase + p) = *(const bf16x8*)(&sA[row][off]);
            }
        }
    }
}

// Per-wave aggregator: one node per wave, zero barriers in the node loop.
// Phase order per iteration minimizes concurrent register live ranges:
//   A-convert (pf/qf die) -> ivn load -> MFMA -> scores -> softmax ->
//   gv (EB) gather issue -> next-node pf/qf prefetch issue -> aggregate.
// gv no longer spans the MFMA/scores phases (round-2's residual spill source).
// __launch_bounds__(256,2): 256-reg budget, 2 blocks/CU = 8 waves/CU.
__global__ __launch_bounds__(256, 2) void agg_kernel(
    const unsigned short* __restrict__ P1, const unsigned short* __restrict__ EB,
    const int* __restrict__ nidx,
    const unsigned short* __restrict__ W2T, const float* __restrict__ b2,
    const float* __restrict__ W3, const float* __restrict__ b3,
    const unsigned short* __restrict__ Q,
    float* __restrict__ out, int NN)
{
    __shared__ bf16x8 sB[2048];          // [kk*8+nt][lane], 32 KB, frag-linear
    __shared__ float  sB2[D], sW3[D];

    const int tid  = threadIdx.x;
    const int lane = tid & 63;
    const int w    = tid >> 6;
    const int m    = lane & 15, q = lane >> 4;

    // stage W2T into fragment-linear order (16B/lane contiguous -> 0 conflicts)
#pragma unroll
    for (int i = 0; i < 8; ++i) {
        int f  = tid + 256 * i;
        int fi = f >> 6, l = f & 63;
        int kk = fi >> 3, nt = fi & 7;
        sB[f] = *(const bf16x8*)(W2T + ((nt * 16 + (l & 15)) << 7) + kk * 32 + (l >> 4) * 8);
    }
    if (tid < D) { sB2[tid] = b2[tid]; sW3[tid] = W3[tid]; }
    __syncthreads();

    const float b3s = b3[0];
    const int stride = gridDim.x << 2;
    int node = (blockIdx.x << 2) + w;

    // ---- pipeline prologue: first node's index row + P1/Q fragments ----
    int iv = 0;
    bf16x8 pf0[4], pf1[4], qf[4];
    if (node < NN) {
        iv = (lane < KN) ? nidx[node * KN + lane] : 0;
        const int ik0 = __shfl(iv, m);
        const int ik1 = __shfl(iv, 16 + m);
        const unsigned short* pr0 = P1 + (long)ik0 * D + q * 8;
        const unsigned short* pr1 = P1 + (long)ik1 * D + q * 8;
        const unsigned short* qr  = Q  + (long)node * D + q * 8;
#pragma unroll
        for (int kk = 0; kk < 4; ++kk) {
            pf0[kk] = *(const bf16x8*)(pr0 + kk * 32);
            pf1[kk] = *(const bf16x8*)(pr1 + kk * 32);
            qf[kk]  = *(const bf16x8*)(qr  + kk * 32);
        }
    }

    for (; node < NN; node += stride) {
        // ---- X = relu(P1 + Q) directly in A-fragment registers ----
        bf16x8 A0[4], A1[4];
#pragma unroll
        for (int kk = 0; kk < 4; ++kk) {
#pragma unroll
            for (int h = 0; h < 8; ++h) {
                float qv = bf2f((unsigned short)qf[kk][h]);
                float v0 = bf2f((unsigned short)pf0[kk][h]) + qv;
                float v1 = bf2f((unsigned short)pf1[kk][h]) + qv;
                A0[kk][h] = (short)f2bf(v0 > 0.f ? v0 : 0.f);
                A1[kk][h] = (short)f2bf(v1 > 0.f ? v1 : 0.f);
            }
        }

        // ---- next node's index row ----
        const int noden = node + stride;
        const bool more = noden < NN;
        int ivn = 0;
        if (more) ivn = (lane < KN) ? nidx[noden * KN + lane] : 0;

        // ---- layer-2 GEMM: [32 x 128] = X @ W2, 8 N-tiles in this wave ----
        f32x4 acc[2][8];
#pragma unroll
        for (int mt = 0; mt < 2; ++mt)
#pragma unroll
            for (int nt = 0; nt < 8; ++nt) acc[mt][nt] = (f32x4){0.f, 0.f, 0.f, 0.f};

#pragma unroll
        for (int kk = 0; kk < 4; ++kk) {
#pragma unroll
            for (int nt = 0; nt < 8; ++nt) {
                bf16x8 b = sB[((kk << 3) + nt) * 64 + lane];
                acc[0][nt] = __builtin_amdgcn_mfma_f32_16x16x32_bf16(A0[kk], b, acc[0][nt], 0, 0, 0);
                acc[1][nt] = __builtin_amdgcn_mfma_f32_16x16x32_bf16(A1[kk], b, acc[1][nt], 0, 0, 0);
            }
        }

        // ---- scores: relu(acc + b2) . W3, reduced across 16 col-lanes ----
        float s[2][4];
#pragma unroll
        for (int mt = 0; mt < 2; ++mt) {
#pragma unroll
            for (int r = 0; r < 4; ++r) s[mt][r] = 0.f;
#pragma unroll
            for (int nt = 0; nt < 8; ++nt) {
                float bc = sB2[nt * 16 + m], wc = sW3[nt * 16 + m];
#pragma unroll
                for (int r = 0; r < 4; ++r) {
                    float h = acc[mt][nt][r] + bc;
                    s[mt][r] += (h > 0.f ? h : 0.f) * wc;
                }
            }
#pragma unroll
            for (int off = 8; off >= 1; off >>= 1)
#pragma unroll
                for (int r = 0; r < 4; ++r) s[mt][r] += __shfl_xor(s[mt][r], off, 16);
#pragma unroll
            for (int r = 0; r < 4; ++r) s[mt][r] += b3s;
        }

        // ---- softmax over 32 (lane holds k = 16*mt + 4*q + r) ----
        float mx = s[0][0];
#pragma unroll
        for (int mt = 0; mt < 2; ++mt)
#pragma unroll
            for (int r = 0; r < 4; ++r) mx = fmaxf(mx, s[mt][r]);
        mx = fmaxf(mx, __shfl_xor(mx, 16));
        mx = fmaxf(mx, __shfl_xor(mx, 32));
        float e[2][4], sum = 0.f;
#pragma unroll
        for (int mt = 0; mt < 2; ++mt)
#pragma unroll
            for (int r = 0; r < 4; ++r) { e[mt][r] = __expf(s[mt][r] - mx); sum += e[mt][r]; }
        sum += __shfl_xor(sum, 16);
        sum += __shfl_xor(sum, 32);
        const float inv = 1.f / sum;

        // ---- EB gather for current node (post-softmax: short live range) ----
        bf16x8 gv[8];
#pragma unroll
        for (int j = 0; j < 8; ++j) {
            int kj  = 4 * q + (j & 3) + 16 * (j >> 2);
            int ikj = __shfl(iv, kj);
            gv[j] = *(const bf16x8*)(EB + (long)ikj * D + m * 8);
        }

        // ---- prefetch next node's P1/Q fragments (pf/qf regs are dead) ----
        if (more) {
            const int ik0n = __shfl(ivn, m);
            const int ik1n = __shfl(ivn, 16 + m);
            const unsigned short* pr0 = P1 + (long)ik0n * D + q * 8;
            const unsigned short* pr1 = P1 + (long)ik1n * D + q * 8;
            const unsigned short* qr  = Q  + (long)noden * D + q * 8;
#pragma unroll
            for (int kk = 0; kk < 4; ++kk) {
                pf0[kk] = *(const bf16x8*)(pr0 + kk * 32);
                pf1[kk] = *(const bf16x8*)(pr1 + kk * 32);
                qf[kk]  = *(const bf16x8*)(qr  + kk * 32);
            }
        }

        // ---- aggregation from gv ----
        float r8[8] = {0.f, 0.f, 0.f, 0.f, 0.f, 0.f, 0.f, 0.f};
#pragma unroll
        for (int j = 0; j < 8; ++j) {
            float a = e[j >> 2][j & 3] * inv;
#pragma unroll
            for (int h = 0; h < 8; ++h) r8[h] += a * bf2f((unsigned short)gv[j][h]);
        }
#pragma unroll
        for (int h = 0; h < 8; ++h) {
            r8[h] += __shfl_xor(r8[h], 16);
            r8[h] += __shfl_xor(r8[h], 32);
        }
        if (lane < 16) {
            float4 o0 = {r8[0], r8[1], r8[2], r8[3]};
            float4 o1 = {r8[4], r8[5], r8[6], r8[7]};
            *(float4*)(out + (long)node * D + m * 8)     = o0;
            *(float4*)(out + (long)node * D + m * 8 + 4) = o1;
        }

        iv = ivn;
    }
}

// Correct-but-slow fp32 VALU fallback (only if ws is too small).
__global__ __launch_bounds__(128) void naive_kernel(
    const float* __restrict__ emb, const int* __restrict__ vnodes,
    const int* __restrict__ nidx,
    const float* __restrict__ W1, const float* __restrict__ b1,
    const float* __restrict__ W2, const float* __restrict__ b2,
    const float* __restrict__ W3, const float* __restrict__ b3,
    float* __restrict__ out)
{
    __shared__ float sE[KN + 1][D];
    __shared__ float sH[KN][D];
    __shared__ float sH2[KN][D];
    __shared__ float sS[KN];
    __shared__ float sA2[KN];
    const int node = blockIdx.x, tid = threadIdx.x;

    for (int r = 0; r < KN + 1; ++r) {
        int vr = (r < KN) ? nidx[node * KN + r] : vnodes[node];
        sE[r][tid] = emb[(long)vr * D + tid];
    }
    __syncthreads();
    for (int k = 0; k < KN; ++k) {
        float s = b1[tid];
        for (int e = 0; e < D; ++e) s += sE[k][e]  * W1[e * D + tid];
        for (int e = 0; e < D; ++e) s += sE[KN][e] * W1[(D + e) * D + tid];
        sH[k][tid] = s > 0.f ? s : 0.f;
    }
    __syncthreads();
    for (int k = 0; k < KN; ++k) {
        float s = b2[tid];
        for (int e = 0; e < D; ++e) s += sH[k][e] * W2[e * D + tid];
        sH2[k][tid] = s > 0.f ? s : 0.f;
    }
    __syncthreads();
    if (tid < KN) {
        float s = b3[0];
        for (int e = 0; e < D; ++e) s += sH2[tid][e] * W3[e];
        sS[tid] = s;
    }
    __syncthreads();
    if (tid == 0) {
        float mx = sS[0];
        for (int k = 1; k < KN; ++k) mx = fmaxf(mx, sS[k]);
        float sum = 0.f;
        for (int k = 0; k < KN; ++k) { sA2[k] = __expf(sS[k] - mx); sum += sA2[k]; }
        for (int k = 0; k < KN; ++k) sA2[k] /= sum;
    }
    __syncthreads();
    float a = 0.f;
    for (int k = 0; k < KN; ++k) a += sA2[k] * sE[k][tid];
    out[(long)node * D + tid] = a;
}

extern "C" void kernel_launch(void* const* d_in, const int* in_sizes, int n_in,
                              void* d_out, int out_size, void* d_ws, size_t ws_size,
                              hipStream_t stream) {
    const float* emb    = (const float*)d_in[0];
    const int*   vnodes = (const int*)d_in[1];
    const int*   nidx   = (const int*)d_in[2];
    const float* W1     = (const float*)d_in[3];
    const float* b1     = (const float*)d_in[4];
    const float* W2     = (const float*)d_in[5];
    const float* b2     = (const float*)d_in[6];
    const float* W3     = (const float*)d_in[7];
    const float* b3     = (const float*)d_in[8];
    float* out = (float*)d_out;

    const int NV = in_sizes[0] / D;   // 200000
    const int NN = in_sizes[1];       // 20000

    const size_t p1_elems = (size_t)NV * D;
    const size_t q_elems  = (size_t)NN * D;
    const size_t wt_elems = (size_t)D * D;
    const size_t need = (2 * p1_elems + q_elems + 3 * wt_elems) * sizeof(unsigned short);

    if (ws_size >= need) {
        unsigned short* P1   = (unsigned short*)d_ws;
        unsigned short* Q    = P1 + p1_elems;
        unsigned short* W1Tt = Q + q_elems;
        unsigned short* W1Tb = W1Tt + wt_elems;
        unsigned short* W2T  = W1Tb + wt_elems;
        unsigned short* EB   = W2T + wt_elems;

        const int nvBlocks = (NV + 127) / 128;
        const int qBlocks  = (NN + 127) / 128;

        wt_kernel<<<(D * D + 255) / 256, 256, 0, stream>>>(W1, W2, W1Tt, W1Tb, W2T);
        p1q_kernel<<<nvBlocks + qBlocks, 256, 0, stream>>>(
            emb, vnodes, NV, NN, nvBlocks, W1Tt, W1Tb, b1, P1, Q, EB);
        agg_kernel<<<512, 256, 0, stream>>>(
            P1, EB, nidx, W2T, b2, W3, b3, Q, out, NN);
    } else {
        naive_kernel<<<NN, D, 0, stream>>>(emb, vnodes, nidx, W1, b1, W2, b2, W3, b3, out);
    }
}